// Round 7
// baseline (317.025 us; speedup 1.0000x reference)
//
#include <hip/hip_runtime.h>
#include <cmath>
#include <type_traits>

#define B_ 4
#define L_ 2048
#define S_ 2048
#define H_ 16
#define E_ 64
// 1/sqrt(64) * log2(e): exp2 (single v_exp_f32) instead of exp
#define SCALE2 0.18033688011112042f

typedef __attribute__((ext_vector_type(4))) float f32x4;
typedef __attribute__((ext_vector_type(8))) __bf16 bf16x8;
typedef __attribute__((ext_vector_type(8))) unsigned short ushort8;
union FragU { ushort8 u; bf16x8 b; unsigned int d[4]; };

__device__ __forceinline__ unsigned short f2bf(float f) {
    unsigned int u = __float_as_uint(f);
    return (unsigned short)((u + 0x7FFFu + ((u >> 16) & 1u)) >> 16);
}

// pack two fp32 (truncate) into one dword of 2 bf16: {hi[31:16], lo[31:16]}
__device__ __forceinline__ unsigned int pack_bf(float hi, float lo) {
    return __builtin_amdgcn_perm(__float_as_uint(hi), __float_as_uint(lo),
                                 0x07060302u);
}

// ---- Prepass: K [b,s,h,e] fp32 -> Kbf [b,h,s,e] bf16, 16B chunks XOR-swizzled
// within each key row (dst chunk j holds src chunk j^(s&7)).
__global__ __launch_bounds__(256) void conv_k(const float* __restrict__ K,
                                              unsigned short* __restrict__ Kbf) {
    const int idx = blockIdx.x * 256 + threadIdx.x;
    const int j   = idx & 7;
    const int row = idx >> 3;            // (b*H+h)*S + s
    const int s   = row & (S_ - 1);
    const int bh  = row >> 11;
    const int h   = bh & (H_ - 1);
    const int b   = bh >> 4;
    const int jp  = j ^ (s & 7);
    const float* src = K + (((size_t)b * S_ + s) * H_ + h) * E_ + jp * 8;
    f32x4 a = *(const f32x4*)src;
    f32x4 d = *(const f32x4*)(src + 4);
    ushort8 u;
    u[0]=f2bf(a[0]); u[1]=f2bf(a[1]); u[2]=f2bf(a[2]); u[3]=f2bf(a[3]);
    u[4]=f2bf(d[0]); u[5]=f2bf(d[1]); u[6]=f2bf(d[2]); u[7]=f2bf(d[3]);
    *(ushort8*)(Kbf + (size_t)row * E_ + j * 8) = u;
}

// ---- Prepass: V [b,s,h,e] fp32 -> Vt [b,h,e,s'] bf16, transposed per head,
// with the PERMUTED-K interleave baked in: within each 64-key block, stored
// chunk cc (= q*2+half) holds keys {(2*half+d)*16 + q*4 + r : d=0,1; r=0..3},
// then chunks XOR-swizzled by (e&7). Main kernel's V B-frags are then plain
// 16B loads.
__global__ __launch_bounds__(256) void conv_v(const float* __restrict__ V,
                                              unsigned short* __restrict__ Vt) {
    __shared__ unsigned short t[64 * 65];
    const int tid  = threadIdx.x;
    const int sblk = blockIdx.x & 31;
    const int h    = (blockIdx.x >> 5) & 15;
    const int b    = blockIdx.x >> 9;
    const int s0   = sblk * 64;
    for (int i = 0; i < 4; ++i) {
        const int c = tid + i * 256;
        const int sr = c >> 4, e0 = (c & 15) * 4;
        f32x4 a = *(const f32x4*)(V + (((size_t)b * S_ + s0 + sr) * H_ + h) * E_ + e0);
        t[sr * 65 + e0 + 0] = f2bf(a[0]);
        t[sr * 65 + e0 + 1] = f2bf(a[1]);
        t[sr * 65 + e0 + 2] = f2bf(a[2]);
        t[sr * 65 + e0 + 3] = f2bf(a[3]);
    }
    __syncthreads();
    for (int i = 0; i < 2; ++i) {
        const int c  = tid + i * 256;
        const int e  = c >> 3, cc = c & 7;
        const int q  = cc >> 1, half = cc & 1;
        ushort8 u;
        for (int j = 0; j < 8; ++j) {
            const int d = j >> 2, r = j & 3;
            const int key = (2 * half + d) * 16 + q * 4 + r;
            u[j] = t[key * 65 + e];
        }
        *(ushort8*)(Vt + ((size_t)(b * H_ + h) * E_ + e) * S_ + s0
                    + (cc ^ (e & 7)) * 8) = u;
    }
}

// ---- Main, R7: BARRIER-FREE. No LDS at all -- every K/V fragment is read
// directly from global (L2-resident thanks to the XCD pin; Kbf/Vt global
// layouts are bit-identical to the old LDS layouts, staging was a linear
// copy). Rationale: R3/R6 proved barrier-synchronized staging carries a
// structural ~6k-cycle/tile stall regardless of pipeline depth; the LDS
// dedup it buys is worth only ~24us of L2 bandwidth (1.1GB @ 34.5TB/s =
// 32us direct vs 8us staged), while the barriers cost ~45us. Waves now run
// fully independent: per-wave trip count, per-wave diagonal tile, TLP (16
// waves/CU) hides L2 latency.
//   Kept: XCD pin (x=h), complementary qtile pairing (R6: occupancy 25->28),
//   l = P.1 on the MFMA pipe, diag-specialized mask (provably exactly the
//   LAST tile of each wave), setprio around MFMA clusters.
template <bool PRE>
__global__ __launch_bounds__(256, 4) void fattn_kernel(
    const float* __restrict__ Q, const unsigned short* __restrict__ Kbf,
    const unsigned short* __restrict__ Vt, const float* __restrict__ Kf,
    const float* __restrict__ Vf, float* __restrict__ Out)
{
    const int tid  = threadIdx.x;
    const int wave = tid >> 6;
    const int lane = tid & 63;
    const int ln   = lane & 15;
    const int quad = lane >> 4;
    const int h = blockIdx.x;            // id%8 == h%8 -> per-(b,h) XCD pin
    const int b = blockIdx.z;
    // Complementary pairing (bijective in y for fixed (x,z)): co-resident
    // blocks get qtiles {t, 15-t, (t+8)&15, 15-((t+8)&15)} -> equal per-CU work.
    const int tt = (blockIdx.y + ((blockIdx.z >> 1) << 3)) & 15;
    const int qtile = (blockIdx.z & 1) ? (15 - tt) : tt;
    const int q0 = qtile * 128;
    const int qw = q0 + wave * 32;       // this wave's 32 q-rows
    const int p7 = ln & 7;

    // Q fragments (B-operand for S^T; n=ln, k=c*32+quad*8+j), pre-scaled.
    FragU qf[2][2];
    #pragma unroll
    for (int g = 0; g < 2; ++g) {
        const float* qp = Q + (((size_t)b * L_ + (qw + g * 16 + ln)) * H_ + h) * E_;
        #pragma unroll
        for (int c = 0; c < 2; ++c) {
            const int e0 = c * 32 + quad * 8;
            f32x4 lo = *(const f32x4*)(qp + e0);
            f32x4 hi = *(const f32x4*)(qp + e0 + 4);
            ushort8 u;
            u[0]=f2bf(lo[0]*SCALE2); u[1]=f2bf(lo[1]*SCALE2);
            u[2]=f2bf(lo[2]*SCALE2); u[3]=f2bf(lo[3]*SCALE2);
            u[4]=f2bf(hi[0]*SCALE2); u[5]=f2bf(hi[1]*SCALE2);
            u[6]=f2bf(hi[2]*SCALE2); u[7]=f2bf(hi[3]*SCALE2);
            qf[g][c].u = u;
        }
    }

    FragU onef;                          // all-ones bf16 B-frag for l = P.1
    #pragma unroll
    for (int j = 0; j < 8; ++j) onef.u[j] = 0x3F80;

    f32x4 o[2][4];
    #pragma unroll
    for (int g = 0; g < 2; ++g)
        #pragma unroll
        for (int et = 0; et < 4; ++et) o[g][et] = f32x4{0.f, 0.f, 0.f, 0.f};
    f32x4 lacc[2];
    lacc[0] = f32x4{0.f, 0.f, 0.f, 0.f};
    lacc[1] = f32x4{0.f, 0.f, 0.f, 0.f};

    const unsigned short* kbh = Kbf + (size_t)(b * H_ + h) * S_ * E_;
    const unsigned short* vbh = Vt  + (size_t)(b * H_ + h) * E_ * S_;
    const float* kf32 = Kf + (((size_t)b * S_) * H_ + h) * E_;
    const float* vf32 = Vf + (((size_t)b * S_) * H_ + h) * E_;

    // Tiles this wave needs: keys 0 .. qw+31. The LAST tile is provably the
    // only one needing the causal mask: mask needed iff k0+63 > qw; active
    // iff k0 <= qw+31; with k0 mult of 64 and qw mult of 32 exactly one k0
    // satisfies qw-62 <= k0 <= qw+31, and it is the last active tile.
    const int ntw = ((qw + 31) >> 6) + 1;

    auto tile = [&](int kt, auto masked) {
        const int k0 = kt * 64;
        // ---- K fragments: 8 x 16B direct loads (L2 hits).
        // Address algebra identical to the old LDS read: stored chunk cs at
        // row s holds original chunk cs^(s&7); we want chunks quad / 4+quad.
        FragU kf[8];
        if constexpr (PRE) {
            #pragma unroll
            for (int n = 0; n < 4; ++n) {
                const unsigned short* kr = kbh + (size_t)(k0 + n * 16 + ln) * E_;
                kf[2*n  ].u = *(const ushort8*)(kr + ((quad    ) ^ p7) * 8);
                kf[2*n+1].u = *(const ushort8*)(kr + ((4 + quad) ^ p7) * 8);
            }
        } else {
            #pragma unroll
            for (int n = 0; n < 4; ++n) {
                const float* kr = kf32 + (size_t)(k0 + n * 16 + ln) * (H_ * E_);
                #pragma unroll
                for (int c = 0; c < 2; ++c) {
                    f32x4 a = *(const f32x4*)(kr + (c * 4 + quad) * 8);
                    f32x4 d = *(const f32x4*)(kr + (c * 4 + quad) * 8 + 4);
                    ushort8 u;
                    u[0]=f2bf(a[0]); u[1]=f2bf(a[1]); u[2]=f2bf(a[2]); u[3]=f2bf(a[3]);
                    u[4]=f2bf(d[0]); u[5]=f2bf(d[1]); u[6]=f2bf(d[2]); u[7]=f2bf(d[3]);
                    kf[2*n+c].u = u;
                }
            }
        }
        // ---- V fragments: issue now so flight hides under QK+softmax.
        FragU vf[8];
        if constexpr (PRE) {
            #pragma unroll
            for (int et = 0; et < 4; ++et) {
                const unsigned short* vr = vbh + (size_t)(et * 16 + ln) * S_ + k0;
                vf[2*et  ].u = *(const ushort8*)(vr + ((2 * quad    ) ^ p7) * 8);
                vf[2*et+1].u = *(const ushort8*)(vr + ((2 * quad + 1) ^ p7) * 8);
            }
        } else {
            #pragma unroll
            for (int et = 0; et < 4; ++et) {
                const int e = et * 16 + ln;
                #pragma unroll
                for (int half = 0; half < 2; ++half) {
                    ushort8 u;
                    #pragma unroll
                    for (int j = 0; j < 8; ++j) {
                        const int key = half * 32 + (j >> 2) * 16 + quad * 4 + (j & 3);
                        u[j] = f2bf(vf32[(size_t)(k0 + key) * (H_ * E_) + e]);
                    }
                    vf[2*et+half].u = u;
                }
            }
        }

        // ---- S^T = K.Q^T, softmax, pack P (bf16) in-register.
        FragU pf[2][2];
        __builtin_amdgcn_s_setprio(1);
        #pragma unroll
        for (int n = 0; n < 4; ++n) {
            #pragma unroll
            for (int g = 0; g < 2; ++g) {
                f32x4 acc = f32x4{0.f, 0.f, 0.f, 0.f};
                acc = __builtin_amdgcn_mfma_f32_16x16x32_bf16(kf[2*n].b,   qf[g][0].b, acc, 0, 0, 0);
                acc = __builtin_amdgcn_mfma_f32_16x16x32_bf16(kf[2*n+1].b, qf[g][1].b, acc, 0, 0, 0);
                float p[4];
                #pragma unroll
                for (int r = 0; r < 4; ++r) {
                    float v = __builtin_exp2f(acc[r]);
                    if constexpr (decltype(masked)::value) {
                        const int key  = k0 + n * 16 + quad * 4 + r;
                        const int qrow = qw + g * 16 + ln;
                        v = (key <= qrow) ? v : 0.f;
                    }
                    p[r] = v;
                }
                pf[g][n >> 1].d[(n & 1) * 2 + 0] = pack_bf(p[1], p[0]);
                pf[g][n >> 1].d[(n & 1) * 2 + 1] = pack_bf(p[3], p[2]);
            }
        }
        // ---- l += P.1 (MFMA pipe); O += P.V.
        #pragma unroll
        for (int g = 0; g < 2; ++g) {
            lacc[g] = __builtin_amdgcn_mfma_f32_16x16x32_bf16(pf[g][0].b, onef.b, lacc[g], 0, 0, 0);
            lacc[g] = __builtin_amdgcn_mfma_f32_16x16x32_bf16(pf[g][1].b, onef.b, lacc[g], 0, 0, 0);
        }
        #pragma unroll
        for (int et = 0; et < 4; ++et) {
            #pragma unroll
            for (int g = 0; g < 2; ++g) {
                o[g][et] = __builtin_amdgcn_mfma_f32_16x16x32_bf16(pf[g][0].b, vf[2*et].b,   o[g][et], 0, 0, 0);
                o[g][et] = __builtin_amdgcn_mfma_f32_16x16x32_bf16(pf[g][1].b, vf[2*et+1].b, o[g][et], 0, 0, 0);
            }
        }
        __builtin_amdgcn_s_setprio(0);
    };

    for (int kt = 0; kt + 1 < ntw; ++kt)
        tile(kt, std::integral_constant<bool, false>{});
    tile(ntw - 1, std::integral_constant<bool, true>{});

    // Epilogue: lacc[g][r] holds l for row quad*4+r of group g on THIS lane
    // (C-layout row = quad*4 + reg, every col identical) -- no shuffles.
    #pragma unroll
    for (int g = 0; g < 2; ++g) {
        #pragma unroll
        for (int r = 0; r < 4; ++r) {
            const float invr = 1.f / lacc[g][r];
            float* op = Out + (((size_t)b * L_ + (qw + g * 16 + quad * 4 + r)) * H_ + h) * E_;
            #pragma unroll
            for (int et = 0; et < 4; ++et)
                op[et * 16 + ln] = o[g][et][r] * invr;
        }
    }
}

extern "C" void kernel_launch(void* const* d_in, const int* in_sizes, int n_in,
                              void* d_out, int out_size, void* d_ws, size_t ws_size,
                              hipStream_t stream) {
    const float* Q = (const float*)d_in[0];
    const float* K = (const float*)d_in[1];
    const float* V = (const float*)d_in[2];
    // d_in[3] (causal mask) applied analytically in-kernel.
    float* Out = (float*)d_out;

    const size_t plane = (size_t)B_ * H_ * S_ * E_;
    unsigned short* Kbf = (unsigned short*)d_ws;
    unsigned short* Vt  = Kbf + plane;

    dim3 grid(H_, L_ / 128, B_);         // x = head: pins (b,h) to one XCD
    if (ws_size >= plane * 2 * sizeof(unsigned short)) {
        conv_k<<<(int)(plane / 8 / 256), 256, 0, stream>>>(K, Kbf);
        conv_v<<<B_ * H_ * (S_ / 64), 256, 0, stream>>>(V, Vt);
        fattn_kernel<true><<<grid, dim3(256), 0, stream>>>(Q, Kbf, Vt, K, V, Out);
    } else {
        fattn_kernel<false><<<grid, dim3(256), 0, stream>>>(Q, Kbf, Vt, K, V, Out);
    }
}

// Round 8
// 228.185 us; speedup vs baseline: 1.3893x; 1.3893x over previous
//
#include <hip/hip_runtime.h>
#include <cmath>
#include <type_traits>

#define B_ 4
#define L_ 2048
#define S_ 2048
#define H_ 16
#define E_ 64
// 1/sqrt(64) * log2(e): exp2 (single v_exp_f32) instead of exp
#define SCALE2 0.18033688011112042f

typedef __attribute__((ext_vector_type(4))) float f32x4;
typedef __attribute__((ext_vector_type(8))) __bf16 bf16x8;
typedef __attribute__((ext_vector_type(8))) unsigned short ushort8;
union FragU { ushort8 u; bf16x8 b; unsigned int d[4]; };

__device__ __forceinline__ unsigned short f2bf(float f) {
    unsigned int u = __float_as_uint(f);
    return (unsigned short)((u + 0x7FFFu + ((u >> 16) & 1u)) >> 16);
}

// pack two fp32 (truncate) into one dword of 2 bf16: {hi[31:16], lo[31:16]}
__device__ __forceinline__ unsigned int pack_bf(float hi, float lo) {
    return __builtin_amdgcn_perm(__float_as_uint(hi), __float_as_uint(lo),
                                 0x07060302u);
}

__device__ __forceinline__ void gload_lds16(const void* g, void* l) {
    __builtin_amdgcn_global_load_lds(
        (const __attribute__((address_space(1))) void*)g,
        (__attribute__((address_space(3))) void*)l, 16, 0, 0);
}

// ---- Prepass: K [b,s,h,e] fp32 -> Kbf [b,h,s,e] bf16, 16B chunks XOR-swizzled
// within each key row (dst chunk j holds src chunk j^(s&7)).
__global__ __launch_bounds__(256) void conv_k(const float* __restrict__ K,
                                              unsigned short* __restrict__ Kbf) {
    const int idx = blockIdx.x * 256 + threadIdx.x;
    const int j   = idx & 7;
    const int row = idx >> 3;            // (b*H+h)*S + s
    const int s   = row & (S_ - 1);
    const int bh  = row >> 11;
    const int h   = bh & (H_ - 1);
    const int b   = bh >> 4;
    const int jp  = j ^ (s & 7);
    const float* src = K + (((size_t)b * S_ + s) * H_ + h) * E_ + jp * 8;
    f32x4 a = *(const f32x4*)src;
    f32x4 d = *(const f32x4*)(src + 4);
    ushort8 u;
    u[0]=f2bf(a[0]); u[1]=f2bf(a[1]); u[2]=f2bf(a[2]); u[3]=f2bf(a[3]);
    u[4]=f2bf(d[0]); u[5]=f2bf(d[1]); u[6]=f2bf(d[2]); u[7]=f2bf(d[3]);
    *(ushort8*)(Kbf + (size_t)row * E_ + j * 8) = u;
}

// ---- Prepass: V [b,s,h,e] fp32 -> Vt bf16 in DIRECT-READ layout:
// Vt[b,h][kblock][et][c][lane][8] where the main kernel's vf fragment for
// (et, c) at lane (quad*16+ln) is the contiguous 16B at
//   vtb + (2*et+c)*512 + lane*8        (vtb = plane + kblock*4096)
// holding V[key = k0+(2c+(j>>2))*16+quad*4+(j&3)][e = et*16+ln] at elem j --
// exactly the PV B-frag mapping. Per (et,c) instruction the wave reads 1KB
// CONTIGUOUS: perfect coalescing, no swizzle, no LDS round-trip.
__global__ __launch_bounds__(256) void conv_v(const float* __restrict__ V,
                                              unsigned short* __restrict__ Vt) {
    __shared__ unsigned short t[64 * 65];
    const int tid  = threadIdx.x;
    const int sblk = blockIdx.x & 31;
    const int h    = (blockIdx.x >> 5) & 15;
    const int b    = blockIdx.x >> 9;
    const int s0   = sblk * 64;
    for (int i = 0; i < 4; ++i) {
        const int c = tid + i * 256;
        const int sr = c >> 4, e0 = (c & 15) * 4;
        f32x4 a = *(const f32x4*)(V + (((size_t)b * S_ + s0 + sr) * H_ + h) * E_ + e0);
        t[sr * 65 + e0 + 0] = f2bf(a[0]);
        t[sr * 65 + e0 + 1] = f2bf(a[1]);
        t[sr * 65 + e0 + 2] = f2bf(a[2]);
        t[sr * 65 + e0 + 3] = f2bf(a[3]);
    }
    __syncthreads();
    for (int i = 0; i < 2; ++i) {
        const int m  = tid + i * 256;        // 0..511: (et,c,quad,ln) packed
        const int et = m >> 7;
        const int c  = (m >> 6) & 1;
        const int qd = (m >> 4) & 3;
        const int l2 = m & 15;
        ushort8 u;
        for (int j = 0; j < 8; ++j) {
            const int kk = (2 * c + (j >> 2)) * 16 + qd * 4 + (j & 3);
            u[j] = t[kk * 65 + et * 16 + l2];
        }
        *(ushort8*)(Vt + (size_t)(b * H_ + h) * (S_ * E_)
                    + (size_t)sblk * 4096 + (size_t)m * 8) = u;
    }
}

// ---- Main, R8 hybrid: K staged in LDS (proven R5 skeleton: 2x8KB dbuf,
// __syncthreads, depth-1 gload_lds); V read DIRECT from L2 in the
// coalescing-native Vt layout (1KB contiguous per frag-load). Rationale:
// per-pipe accounting of R5 showed LDS-read is the hottest pipe (~50%:
// 256 b128 reads/CU-iter) and the barrier drains the K+V DMA payload; V
// direct halves LDS pressure and barrier payload while its latency hides
// under QK+softmax (et0/1 issued before QK; et+2 prefetched in PV loop).
// R7's failure modes addressed: only 4 V-frags live (no spill; ~120 regs
// total inc. AGPR) and the new layout reads are fully coalesced.
//   Kept: XCD pin (x=h), complementary qtile pairing, l = P.1 on the MFMA
//   pipe, diag-specialized mask (provably the last tile only), setprio.
template <bool PRE>
__global__ __launch_bounds__(256, 4) void fattn_kernel(
    const float* __restrict__ Q, const unsigned short* __restrict__ Kbf,
    const unsigned short* __restrict__ Vt, const float* __restrict__ Kf,
    const float* __restrict__ Vf, float* __restrict__ Out)
{
    const int tid  = threadIdx.x;
    const int wave = tid >> 6;
    const int lane = tid & 63;
    const int ln   = lane & 15;
    const int quad = lane >> 4;
    const int h = blockIdx.x;            // id%8 == h%8 -> per-(b,h) XCD pin
    const int b = blockIdx.z;
    // Complementary pairing (bijective in y for fixed (x,z)): co-resident
    // blocks get qtiles {t, 15-t, (t+8)&15, 15-((t+8)&15)} -> equal per-CU work.
    const int tt = (blockIdx.y + ((blockIdx.z >> 1) << 3)) & 15;
    const int qtile = (blockIdx.z & 1) ? (15 - tt) : tt;
    const int q0 = qtile * 128;
    const int qw = q0 + wave * 32;       // this wave's 32 q-rows
    const int p7 = ln & 7;

    __shared__ __align__(16) unsigned short ldsK[2][64 * 64];  // [key][e] swz

    // Q fragments (B-operand for S^T; n=ln, k=c*32+quad*8+j), pre-scaled.
    FragU qf[2][2];
    #pragma unroll
    for (int g = 0; g < 2; ++g) {
        const float* qp = Q + (((size_t)b * L_ + (qw + g * 16 + ln)) * H_ + h) * E_;
        #pragma unroll
        for (int c = 0; c < 2; ++c) {
            const int e0 = c * 32 + quad * 8;
            f32x4 lo = *(const f32x4*)(qp + e0);
            f32x4 hi = *(const f32x4*)(qp + e0 + 4);
            ushort8 u;
            u[0]=f2bf(lo[0]*SCALE2); u[1]=f2bf(lo[1]*SCALE2);
            u[2]=f2bf(lo[2]*SCALE2); u[3]=f2bf(lo[3]*SCALE2);
            u[4]=f2bf(hi[0]*SCALE2); u[5]=f2bf(hi[1]*SCALE2);
            u[6]=f2bf(hi[2]*SCALE2); u[7]=f2bf(hi[3]*SCALE2);
            qf[g][c].u = u;
        }
    }

    FragU onef;                          // all-ones bf16 B-frag for l = P.1
    #pragma unroll
    for (int j = 0; j < 8; ++j) onef.u[j] = 0x3F80;

    f32x4 o[2][4];
    #pragma unroll
    for (int g = 0; g < 2; ++g)
        #pragma unroll
        for (int et = 0; et < 4; ++et) o[g][et] = f32x4{0.f, 0.f, 0.f, 0.f};
    f32x4 lacc[2];
    lacc[0] = f32x4{0.f, 0.f, 0.f, 0.f};
    lacc[1] = f32x4{0.f, 0.f, 0.f, 0.f};

    const unsigned short* kbh = Kbf + (size_t)(b * H_ + h) * S_ * E_;
    const unsigned short* vbh = Vt  + (size_t)(b * H_ + h) * (S_ * E_);
    const float* kf32 = Kf + (((size_t)b * S_) * H_ + h) * E_;
    const float* vf32 = Vf + (((size_t)b * S_) * H_ + h) * E_;

    auto STAGE_K = [&](int bsel, int kt2) {
        const int k0s = kt2 * 64;
        if constexpr (PRE) {
            const unsigned short* ktb = kbh + (size_t)k0s * E_;
            #pragma unroll
            for (int i = 0; i < 2; ++i) {          // K tile: 8KB linear DMA
                const int slot0 = wave * 128 + i * 64;
                gload_lds16(ktb + (size_t)(slot0 + lane) * 8,
                            &ldsK[bsel][slot0 * 8]);
            }
        } else {
            #pragma unroll
            for (int i = 0; i < 2; ++i) {          // fp32 fallback staging
                const int c = tid + i * 256;
                const int key = c >> 3, j = c & 7, jp = j ^ (key & 7);
                const float* src = kf32 + (size_t)(k0s + key) * (H_ * E_) + jp * 8;
                f32x4 a = *(const f32x4*)src, d = *(const f32x4*)(src + 4);
                ushort8 u;
                u[0]=f2bf(a[0]); u[1]=f2bf(a[1]); u[2]=f2bf(a[2]); u[3]=f2bf(a[3]);
                u[4]=f2bf(d[0]); u[5]=f2bf(d[1]); u[6]=f2bf(d[2]); u[7]=f2bf(d[3]);
                *(ushort8*)&ldsK[bsel][key * 64 + j * 8] = u;
            }
        }
    };

    // fp32 fallback V-frag (PRE=false only).
    auto vload_f32 = [&](int k0s, int et, int c, FragU& dst) {
        ushort8 u;
        #pragma unroll
        for (int j = 0; j < 8; ++j) {
            const int key = k0s + (2 * c + (j >> 2)) * 16 + quad * 4 + (j & 3);
            u[j] = f2bf(vf32[(size_t)key * (H_ * E_) + et * 16 + ln]);
        }
        dst.u = u;
    };

    const int ntiles = 2 * qtile + 2;    // keys 0 .. q0+127
    STAGE_K(0, 0);
    int cur = 0;
    for (int kt = 0; kt < ntiles; ++kt) {
        const int k0 = kt * 64;
        // Drains own vmcnt (K tile kt resident) AND guarantees every wave
        // finished reading buf cur^1 before we overwrite it.
        __syncthreads();
        if (kt + 1 < ntiles) STAGE_K(cur ^ 1, kt + 1);

        if (k0 <= qw + 31) {             // wave-uniform skip of masked tiles
            const unsigned short* bK  = ldsK[cur];
            const unsigned short* vtb = vbh + (size_t)kt * 4096;

            // V frags for et=0,1 issued NOW: ~700cyc of QK+softmax cover.
            FragU vc0, vc1, vn0, vn1;
            if constexpr (PRE) {
                vc0.u = *(const ushort8*)(vtb + 0 * 512 + lane * 8);
                vc1.u = *(const ushort8*)(vtb + 1 * 512 + lane * 8);
                vn0.u = *(const ushort8*)(vtb + 2 * 512 + lane * 8);
                vn1.u = *(const ushort8*)(vtb + 3 * 512 + lane * 8);
            } else {
                vload_f32(k0, 0, 0, vc0); vload_f32(k0, 0, 1, vc1);
                vload_f32(k0, 1, 0, vn0); vload_f32(k0, 1, 1, vn1);
            }

            __builtin_amdgcn_s_setprio(1);
            FragU pf[2][2];
            // S^T = K.Q^T : A = K-frag (m=key), B = Q-frag (n=qrow).
            // Diag-specialized: the single tile with k0+63 > qw masks BOTH
            // groups (k0 mult of 64, qw of 32 -> k0+63 >= qw+31 > qw+16).
            auto qk_phase = [&](auto masked) {
                #pragma unroll
                for (int n = 0; n < 4; ++n) {
                    FragU kf0, kf1;
                    kf0.u = *(const ushort8*)&bK[(n*16+ln)*64 + ((quad    ) ^ p7) * 8];
                    kf1.u = *(const ushort8*)&bK[(n*16+ln)*64 + ((4 + quad) ^ p7) * 8];
                    #pragma unroll
                    for (int g = 0; g < 2; ++g) {
                        f32x4 acc = f32x4{0.f, 0.f, 0.f, 0.f};
                        acc = __builtin_amdgcn_mfma_f32_16x16x32_bf16(kf0.b, qf[g][0].b, acc, 0, 0, 0);
                        acc = __builtin_amdgcn_mfma_f32_16x16x32_bf16(kf1.b, qf[g][1].b, acc, 0, 0, 0);
                        float p[4];
                        #pragma unroll
                        for (int r = 0; r < 4; ++r) {
                            float v = __builtin_exp2f(acc[r]);
                            if constexpr (decltype(masked)::value) {
                                const int key  = k0 + n * 16 + quad * 4 + r;
                                const int qrow = qw + g * 16 + ln;
                                v = (key <= qrow) ? v : 0.f;
                            }
                            p[r] = v;
                        }
                        pf[g][n >> 1].d[(n & 1) * 2 + 0] = pack_bf(p[1], p[0]);
                        pf[g][n >> 1].d[(n & 1) * 2 + 1] = pack_bf(p[3], p[2]);
                    }
                }
            };
            if (k0 + 63 > qw) qk_phase(std::integral_constant<bool, true>{});
            else              qk_phase(std::integral_constant<bool, false>{});

            // l += P.1 on the MFMA pipe.
            #pragma unroll
            for (int g = 0; g < 2; ++g) {
                lacc[g] = __builtin_amdgcn_mfma_f32_16x16x32_bf16(pf[g][0].b, onef.b, lacc[g], 0, 0, 0);
                lacc[g] = __builtin_amdgcn_mfma_f32_16x16x32_bf16(pf[g][1].b, onef.b, lacc[g], 0, 0, 0);
            }
            // O += P.V with 1-et lookahead (static rotation, no arrays).
            #pragma unroll
            for (int et = 0; et < 4; ++et) {
                FragU va = vc0, vb = vc1;
                vc0 = vn0; vc1 = vn1;
                if (et < 2) {
                    if constexpr (PRE) {
                        vn0.u = *(const ushort8*)(vtb + (2*(et+2)    ) * 512 + lane * 8);
                        vn1.u = *(const ushort8*)(vtb + (2*(et+2) + 1) * 512 + lane * 8);
                    } else {
                        vload_f32(k0, et + 2, 0, vn0);
                        vload_f32(k0, et + 2, 1, vn1);
                    }
                }
                #pragma unroll
                for (int g = 0; g < 2; ++g) {
                    o[g][et] = __builtin_amdgcn_mfma_f32_16x16x32_bf16(pf[g][0].b, va.b, o[g][et], 0, 0, 0);
                    o[g][et] = __builtin_amdgcn_mfma_f32_16x16x32_bf16(pf[g][1].b, vb.b, o[g][et], 0, 0, 0);
                }
            }
            __builtin_amdgcn_s_setprio(0);
        }
        cur ^= 1;
    }

    // Epilogue: lacc[g][r] holds l for row quad*4+r of group g on THIS lane
    // (C-layout row = quad*4 + reg, every col identical) -- no shuffles.
    #pragma unroll
    for (int g = 0; g < 2; ++g) {
        #pragma unroll
        for (int r = 0; r < 4; ++r) {
            const float invr = 1.f / lacc[g][r];
            float* op = Out + (((size_t)b * L_ + (qw + g * 16 + quad * 4 + r)) * H_ + h) * E_;
            #pragma unroll
            for (int et = 0; et < 4; ++et)
                op[et * 16 + ln] = o[g][et][r] * invr;
        }
    }
}

extern "C" void kernel_launch(void* const* d_in, const int* in_sizes, int n_in,
                              void* d_out, int out_size, void* d_ws, size_t ws_size,
                              hipStream_t stream) {
    const float* Q = (const float*)d_in[0];
    const float* K = (const float*)d_in[1];
    const float* V = (const float*)d_in[2];
    // d_in[3] (causal mask) applied analytically in-kernel.
    float* Out = (float*)d_out;

    const size_t plane = (size_t)B_ * H_ * S_ * E_;
    unsigned short* Kbf = (unsigned short*)d_ws;
    unsigned short* Vt  = Kbf + plane;

    dim3 grid(H_, L_ / 128, B_);         // x = head: pins (b,h) to one XCD
    if (ws_size >= plane * 2 * sizeof(unsigned short)) {
        conv_k<<<(int)(plane / 8 / 256), 256, 0, stream>>>(K, Kbf);
        conv_v<<<B_ * H_ * (S_ / 64), 256, 0, stream>>>(V, Vt);
        fattn_kernel<true><<<grid, dim3(256), 0, stream>>>(Q, Kbf, Vt, K, V, Out);
    } else {
        fattn_kernel<false><<<grid, dim3(256), 0, stream>>>(Q, Kbf, Vt, K, V, Out);
    }
}

// Round 9
// 225.481 us; speedup vs baseline: 1.4060x; 1.0120x over previous
//
#include <hip/hip_runtime.h>
#include <cmath>
#include <type_traits>

#define B_ 4
#define L_ 2048
#define S_ 2048
#define H_ 16
#define E_ 64
// 1/sqrt(64) * log2(e): exp2 (single v_exp_f32) instead of exp
#define SCALE2 0.18033688011112042f

typedef __attribute__((ext_vector_type(4))) float f32x4;
typedef __attribute__((ext_vector_type(8))) __bf16 bf16x8;
typedef __attribute__((ext_vector_type(8))) unsigned short ushort8;
union FragU { ushort8 u; bf16x8 b; unsigned int d[4]; };

__device__ __forceinline__ unsigned short f2bf(float f) {
    unsigned int u = __float_as_uint(f);
    return (unsigned short)((u + 0x7FFFu + ((u >> 16) & 1u)) >> 16);
}

// pack two fp32 (truncate) into one dword of 2 bf16: {hi[31:16], lo[31:16]}
__device__ __forceinline__ unsigned int pack_bf(float hi, float lo) {
    return __builtin_amdgcn_perm(__float_as_uint(hi), __float_as_uint(lo),
                                 0x07060302u);
}

// ---- Prepass: K [b,s,h,e] fp32 -> Kbf [b,h,s,e] bf16, 16B chunks XOR-swizzled
// within each key row (dst chunk j holds src chunk j^(s&7)). A kf frag-pair
// read in the main kernel covers a CONTIGUOUS 2KB span (16 rows x 128B).
__global__ __launch_bounds__(256) void conv_k(const float* __restrict__ K,
                                              unsigned short* __restrict__ Kbf) {
    const int idx = blockIdx.x * 256 + threadIdx.x;
    const int j   = idx & 7;
    const int row = idx >> 3;            // (b*H+h)*S + s
    const int s   = row & (S_ - 1);
    const int bh  = row >> 11;
    const int h   = bh & (H_ - 1);
    const int b   = bh >> 4;
    const int jp  = j ^ (s & 7);
    const float* src = K + (((size_t)b * S_ + s) * H_ + h) * E_ + jp * 8;
    f32x4 a = *(const f32x4*)src;
    f32x4 d = *(const f32x4*)(src + 4);
    ushort8 u;
    u[0]=f2bf(a[0]); u[1]=f2bf(a[1]); u[2]=f2bf(a[2]); u[3]=f2bf(a[3]);
    u[4]=f2bf(d[0]); u[5]=f2bf(d[1]); u[6]=f2bf(d[2]); u[7]=f2bf(d[3]);
    *(ushort8*)(Kbf + (size_t)row * E_ + j * 8) = u;
}

// ---- Prepass: V [b,s,h,e] fp32 -> Vt bf16 in DIRECT-READ layout:
// Vt[b,h][kblock][et][c][lane][8]: main kernel's vf frag (et,c) at lane is
// the contiguous 16B at vtb + (2*et+c)*512 + lane*8, holding
// V[key = k0+(2c+(j>>2))*16+quad*4+(j&3)][e = et*16+ln] at elem j -- the PV
// B-frag mapping. 1KB CONTIGUOUS per wave-instruction: perfect coalescing.
__global__ __launch_bounds__(256) void conv_v(const float* __restrict__ V,
                                              unsigned short* __restrict__ Vt) {
    __shared__ unsigned short t[64 * 65];
    const int tid  = threadIdx.x;
    const int sblk = blockIdx.x & 31;
    const int h    = (blockIdx.x >> 5) & 15;
    const int b    = blockIdx.x >> 9;
    const int s0   = sblk * 64;
    for (int i = 0; i < 4; ++i) {
        const int c = tid + i * 256;
        const int sr = c >> 4, e0 = (c & 15) * 4;
        f32x4 a = *(const f32x4*)(V + (((size_t)b * S_ + s0 + sr) * H_ + h) * E_ + e0);
        t[sr * 65 + e0 + 0] = f2bf(a[0]);
        t[sr * 65 + e0 + 1] = f2bf(a[1]);
        t[sr * 65 + e0 + 2] = f2bf(a[2]);
        t[sr * 65 + e0 + 3] = f2bf(a[3]);
    }
    __syncthreads();
    for (int i = 0; i < 2; ++i) {
        const int m  = tid + i * 256;        // 0..511: (et,c,quad,ln) packed
        const int et = m >> 7;
        const int c  = (m >> 6) & 1;
        const int qd = (m >> 4) & 3;
        const int l2 = m & 15;
        ushort8 u;
        for (int j = 0; j < 8; ++j) {
            const int kk = (2 * c + (j >> 2)) * 16 + qd * 4 + (j & 3);
            u[j] = t[kk * 65 + et * 16 + l2];
        }
        *(ushort8*)(Vt + (size_t)(b * H_ + h) * (S_ * E_)
                    + (size_t)sblk * 4096 + (size_t)m * 8) = u;
    }
}

// ---- Main, R9: BARRIER-FREE, register-disciplined. No LDS, no barriers,
// no DMA: every K/V frag is a coalesced direct load from L2 (XCD-pinned
// working set = 8 (b,h) x 512KB = 4MB = one L2). Three staging structures
// (R3 depth / R6 counted-vmcnt / R8 LDS-halving) all failed to beat R5's
// 80us because the limiter is the barrier rendezvous itself (~6k cyc/tile
// vs ~800 compute) plus the intra-CU tail (time-avg occupancy 25% vs 50%
// launched). Waves here are fully independent: per-wave trip count, tail
// iterations cost their own ~1.2k-cycle path, not a 4-wave rendezvous.
// R7's failure modes fixed: V from R8's coalescing-native Vt (1KB/instr;
// R7's was 4KB-stride scatter), K frag-pairs cover contiguous 2KB spans,
// and phases are sequenced so kf[8] dies before vf[8] is born (peak ~115
// regs, no spill -- R7 held both and spilled 296MB to scratch).
//   Kept: XCD pin (x=h), complementary qtile pairing, l = P.1 on the MFMA
//   pipe, diag-specialized mask (provably the last tile only), setprio.
template <bool PRE>
__global__ __launch_bounds__(256, 4) void fattn_kernel(
    const float* __restrict__ Q, const unsigned short* __restrict__ Kbf,
    const unsigned short* __restrict__ Vt, const float* __restrict__ Kf,
    const float* __restrict__ Vf, float* __restrict__ Out)
{
    const int tid  = threadIdx.x;
    const int wave = tid >> 6;
    const int lane = tid & 63;
    const int ln   = lane & 15;
    const int quad = lane >> 4;
    const int h = blockIdx.x;            // id%8 == h%8 -> per-(b,h) XCD pin
    const int b = blockIdx.z;
    // Complementary pairing (bijective in y for fixed (x,z)): co-resident
    // blocks get qtiles {t, 15-t, (t+8)&15, 15-((t+8)&15)} -> equal per-CU work.
    const int tt = (blockIdx.y + ((blockIdx.z >> 1) << 3)) & 15;
    const int qtile = (blockIdx.z & 1) ? (15 - tt) : tt;
    const int q0 = qtile * 128;
    const int qw = q0 + wave * 32;       // this wave's 32 q-rows
    const int p7 = ln & 7;

    // Q fragments (B-operand for S^T; n=ln, k=c*32+quad*8+j), pre-scaled.
    FragU qf[2][2];
    #pragma unroll
    for (int g = 0; g < 2; ++g) {
        const float* qp = Q + (((size_t)b * L_ + (qw + g * 16 + ln)) * H_ + h) * E_;
        #pragma unroll
        for (int c = 0; c < 2; ++c) {
            const int e0 = c * 32 + quad * 8;
            f32x4 lo = *(const f32x4*)(qp + e0);
            f32x4 hi = *(const f32x4*)(qp + e0 + 4);
            ushort8 u;
            u[0]=f2bf(lo[0]*SCALE2); u[1]=f2bf(lo[1]*SCALE2);
            u[2]=f2bf(lo[2]*SCALE2); u[3]=f2bf(lo[3]*SCALE2);
            u[4]=f2bf(hi[0]*SCALE2); u[5]=f2bf(hi[1]*SCALE2);
            u[6]=f2bf(hi[2]*SCALE2); u[7]=f2bf(hi[3]*SCALE2);
            qf[g][c].u = u;
        }
    }

    FragU onef;                          // all-ones bf16 B-frag for l = P.1
    #pragma unroll
    for (int j = 0; j < 8; ++j) onef.u[j] = 0x3F80;

    f32x4 o[2][4];
    #pragma unroll
    for (int g = 0; g < 2; ++g)
        #pragma unroll
        for (int et = 0; et < 4; ++et) o[g][et] = f32x4{0.f, 0.f, 0.f, 0.f};
    f32x4 lacc[2];
    lacc[0] = f32x4{0.f, 0.f, 0.f, 0.f};
    lacc[1] = f32x4{0.f, 0.f, 0.f, 0.f};

    const unsigned short* kbh = Kbf + (size_t)(b * H_ + h) * S_ * E_;
    const unsigned short* vbh = Vt  + (size_t)(b * H_ + h) * (S_ * E_);
    const float* kf32 = Kf + (((size_t)b * S_) * H_ + h) * E_;
    const float* vf32 = Vf + (((size_t)b * S_) * H_ + h) * E_;

    // Tiles this wave needs: keys 0 .. qw+31; the LAST tile is provably the
    // only one needing the causal mask (k0 mult of 64, qw mult of 32).
    const int ntw = ((qw + 31) >> 6) + 1;

    auto tile = [&](int kt, auto masked) {
        const int k0 = kt * 64;
        // ---- Phase 1: K frags, 8 coalesced 16B loads (2KB span per pair).
        FragU kf[8];
        if constexpr (PRE) {
            #pragma unroll
            for (int n = 0; n < 4; ++n) {
                const unsigned short* kr = kbh + (size_t)(k0 + n * 16 + ln) * E_;
                kf[2*n  ].u = *(const ushort8*)(kr + ((quad    ) ^ p7) * 8);
                kf[2*n+1].u = *(const ushort8*)(kr + ((4 + quad) ^ p7) * 8);
            }
        } else {
            #pragma unroll
            for (int n = 0; n < 4; ++n) {
                const float* kr = kf32 + (size_t)(k0 + n * 16 + ln) * (H_ * E_);
                #pragma unroll
                for (int c = 0; c < 2; ++c) {
                    f32x4 a = *(const f32x4*)(kr + (c * 4 + quad) * 8);
                    f32x4 d = *(const f32x4*)(kr + (c * 4 + quad) * 8 + 4);
                    ushort8 u;
                    u[0]=f2bf(a[0]); u[1]=f2bf(a[1]); u[2]=f2bf(a[2]); u[3]=f2bf(a[3]);
                    u[4]=f2bf(d[0]); u[5]=f2bf(d[1]); u[6]=f2bf(d[2]); u[7]=f2bf(d[3]);
                    kf[2*n+c].u = u;
                }
            }
        }
        // ---- Phase 2: S^T = K.Q^T + softmax; kf[2n..] die per n.
        FragU pf[2][2];
        __builtin_amdgcn_s_setprio(1);
        #pragma unroll
        for (int n = 0; n < 4; ++n) {
            #pragma unroll
            for (int g = 0; g < 2; ++g) {
                f32x4 acc = f32x4{0.f, 0.f, 0.f, 0.f};
                acc = __builtin_amdgcn_mfma_f32_16x16x32_bf16(kf[2*n].b,   qf[g][0].b, acc, 0, 0, 0);
                acc = __builtin_amdgcn_mfma_f32_16x16x32_bf16(kf[2*n+1].b, qf[g][1].b, acc, 0, 0, 0);
                float p[4];
                #pragma unroll
                for (int r = 0; r < 4; ++r) {
                    float v = __builtin_exp2f(acc[r]);
                    if constexpr (decltype(masked)::value) {
                        const int key  = k0 + n * 16 + quad * 4 + r;
                        const int qrow = qw + g * 16 + ln;
                        v = (key <= qrow) ? v : 0.f;
                    }
                    p[r] = v;
                }
                pf[g][n >> 1].d[(n & 1) * 2 + 0] = pack_bf(p[1], p[0]);
                pf[g][n >> 1].d[(n & 1) * 2 + 1] = pack_bf(p[3], p[2]);
            }
        }
        __builtin_amdgcn_s_setprio(0);
        // Fence: keep V loads BELOW the QK/softmax phase so vf[8] reuses
        // kf[8]'s register slots (R7 held both live -> 296MB scratch spill).
        __builtin_amdgcn_sched_barrier(0);

        // ---- Phase 3: V frags, 8 x 1KB contiguous loads.
        FragU vf[8];
        if constexpr (PRE) {
            const unsigned short* vtb = vbh + (size_t)kt * 4096;
            #pragma unroll
            for (int m = 0; m < 8; ++m)
                vf[m].u = *(const ushort8*)(vtb + m * 512 + lane * 8);
        } else {
            #pragma unroll
            for (int et = 0; et < 4; ++et) {
                #pragma unroll
                for (int c = 0; c < 2; ++c) {
                    ushort8 u;
                    #pragma unroll
                    for (int j = 0; j < 8; ++j) {
                        const int key = k0 + (2 * c + (j >> 2)) * 16 + quad * 4 + (j & 3);
                        u[j] = f2bf(vf32[(size_t)key * (H_ * E_) + et * 16 + ln]);
                    }
                    vf[2*et+c].u = u;
                }
            }
        }
        // ---- Phase 4: l += P.1 ; O += P.V.
        __builtin_amdgcn_s_setprio(1);
        #pragma unroll
        for (int g = 0; g < 2; ++g) {
            lacc[g] = __builtin_amdgcn_mfma_f32_16x16x32_bf16(pf[g][0].b, onef.b, lacc[g], 0, 0, 0);
            lacc[g] = __builtin_amdgcn_mfma_f32_16x16x32_bf16(pf[g][1].b, onef.b, lacc[g], 0, 0, 0);
        }
        #pragma unroll
        for (int et = 0; et < 4; ++et) {
            #pragma unroll
            for (int g = 0; g < 2; ++g) {
                o[g][et] = __builtin_amdgcn_mfma_f32_16x16x32_bf16(pf[g][0].b, vf[2*et].b,   o[g][et], 0, 0, 0);
                o[g][et] = __builtin_amdgcn_mfma_f32_16x16x32_bf16(pf[g][1].b, vf[2*et+1].b, o[g][et], 0, 0, 0);
            }
        }
        __builtin_amdgcn_s_setprio(0);
    };

    for (int kt = 0; kt + 1 < ntw; ++kt)
        tile(kt, std::integral_constant<bool, false>{});
    tile(ntw - 1, std::integral_constant<bool, true>{});

    // Epilogue: lacc[g][r] holds l for row quad*4+r of group g on THIS lane
    // (C-layout row = quad*4 + reg, every col identical) -- no shuffles.
    #pragma unroll
    for (int g = 0; g < 2; ++g) {
        #pragma unroll
        for (int r = 0; r < 4; ++r) {
            const float invr = 1.f / lacc[g][r];
            float* op = Out + (((size_t)b * L_ + (qw + g * 16 + quad * 4 + r)) * H_ + h) * E_;
            #pragma unroll
            for (int et = 0; et < 4; ++et)
                op[et * 16 + ln] = o[g][et][r] * invr;
        }
    }
}

extern "C" void kernel_launch(void* const* d_in, const int* in_sizes, int n_in,
                              void* d_out, int out_size, void* d_ws, size_t ws_size,
                              hipStream_t stream) {
    const float* Q = (const float*)d_in[0];
    const float* K = (const float*)d_in[1];
    const float* V = (const float*)d_in[2];
    // d_in[3] (causal mask) applied analytically in-kernel.
    float* Out = (float*)d_out;

    const size_t plane = (size_t)B_ * H_ * S_ * E_;
    unsigned short* Kbf = (unsigned short*)d_ws;
    unsigned short* Vt  = Kbf + plane;

    dim3 grid(H_, L_ / 128, B_);         // x = head: pins (b,h) to one XCD
    if (ws_size >= plane * 2 * sizeof(unsigned short)) {
        conv_k<<<(int)(plane / 8 / 256), 256, 0, stream>>>(K, Kbf);
        conv_v<<<B_ * H_ * (S_ / 64), 256, 0, stream>>>(V, Vt);
        fattn_kernel<true><<<grid, dim3(256), 0, stream>>>(Q, Kbf, Vt, K, V, Out);
    } else {
        fattn_kernel<false><<<grid, dim3(256), 0, stream>>>(Q, Kbf, Vt, K, V, Out);
    }
}

// Round 11
// 223.687 us; speedup vs baseline: 1.4173x; 1.0080x over previous
//
#include <hip/hip_runtime.h>
#include <cmath>
#include <type_traits>

#define B_ 4
#define L_ 2048
#define S_ 2048
#define H_ 16
#define E_ 64
// 1/sqrt(64) * log2(e): exp2 (single v_exp_f32) instead of exp
#define SCALE2 0.18033688011112042f

typedef __attribute__((ext_vector_type(4))) float f32x4;
typedef __attribute__((ext_vector_type(8))) __bf16 bf16x8;
typedef __attribute__((ext_vector_type(8))) unsigned short ushort8;
union FragU { ushort8 u; bf16x8 b; unsigned int d[4]; };

__device__ __forceinline__ unsigned short f2bf(float f) {
    unsigned int u = __float_as_uint(f);
    return (unsigned short)((u + 0x7FFFu + ((u >> 16) & 1u)) >> 16);
}

// pack two fp32 (truncate) into one dword of 2 bf16: {hi[31:16], lo[31:16]}
__device__ __forceinline__ unsigned int pack_bf(float hi, float lo) {
    return __builtin_amdgcn_perm(__float_as_uint(hi), __float_as_uint(lo),
                                 0x07060302u);
}

// ---- Merged prepass (R10): one block per (b, h, 64-key slice) does BOTH
// K-conversion and V-transpose. Same layouts as before:
//   Kbf [b,h,s,e] bf16, 16B chunks XOR-swizzled within each key row
//     (dst chunk j holds src chunk j^(s&7)); a main-kernel kf frag-pair
//     read covers a contiguous 2KB span.
//   Vt [b,h][kblock][m=(et,c,quad,ln)][8] bf16: vf frag (et,c) at lane is
//     the contiguous 16B at vtb + (2*et+c)*512 + lane*8 holding
//     V[key=k0+(2c+(j>>2))*16+quad*4+(j&3)][e=et*16+ln] -- the PV B-frag
//     mapping; 1KB contiguous per wave-instruction.
// Merging halves launch count; per-block: 32KB fp32 read, 16KB bf16 write.
__global__ __launch_bounds__(256) void conv_kv(const float* __restrict__ K,
                                               const float* __restrict__ V,
                                               unsigned short* __restrict__ Kbf,
                                               unsigned short* __restrict__ Vt) {
    __shared__ unsigned short t[64 * 65];
    const int tid  = threadIdx.x;
    const int sblk = blockIdx.x & 31;
    const int h    = (blockIdx.x >> 5) & 15;
    const int b    = blockIdx.x >> 9;
    const int s0   = sblk * 64;

    // ---- K part: 64 rows x 64 e of this slice (512 16B chunks).
    #pragma unroll
    for (int i = 0; i < 2; ++i) {
        const int c  = tid + i * 256;
        const int sr = c >> 3, j = c & 7;
        const int jp = j ^ (sr & 7);         // s0 is a multiple of 64
        const float* src = K + (((size_t)b * S_ + s0 + sr) * H_ + h) * E_ + jp * 8;
        f32x4 a = *(const f32x4*)src;
        f32x4 d = *(const f32x4*)(src + 4);
        ushort8 u;
        u[0]=f2bf(a[0]); u[1]=f2bf(a[1]); u[2]=f2bf(a[2]); u[3]=f2bf(a[3]);
        u[4]=f2bf(d[0]); u[5]=f2bf(d[1]); u[6]=f2bf(d[2]); u[7]=f2bf(d[3]);
        *(ushort8*)(Kbf + ((size_t)(b * H_ + h) * S_ + s0 + sr) * E_ + j * 8) = u;
    }

    // ---- V part: stage slice to LDS, emit transposed frag-native layout.
    for (int i = 0; i < 4; ++i) {
        const int c = tid + i * 256;
        const int sr = c >> 4, e0 = (c & 15) * 4;
        f32x4 a = *(const f32x4*)(V + (((size_t)b * S_ + s0 + sr) * H_ + h) * E_ + e0);
        t[sr * 65 + e0 + 0] = f2bf(a[0]);
        t[sr * 65 + e0 + 1] = f2bf(a[1]);
        t[sr * 65 + e0 + 2] = f2bf(a[2]);
        t[sr * 65 + e0 + 3] = f2bf(a[3]);
    }
    __syncthreads();
    #pragma unroll
    for (int i = 0; i < 2; ++i) {
        const int m  = tid + i * 256;        // 0..511: (et,c,quad,ln) packed
        const int et = m >> 7;
        const int c  = (m >> 6) & 1;
        const int qd = (m >> 4) & 3;
        const int l2 = m & 15;
        ushort8 u;
        #pragma unroll
        for (int j = 0; j < 8; ++j) {
            const int kk = (2 * c + (j >> 2)) * 16 + qd * 4 + (j & 3);
            u[j] = t[kk * 65 + et * 16 + l2];
        }
        *(ushort8*)(Vt + (size_t)(b * H_ + h) * (S_ * E_)
                    + (size_t)sblk * 4096 + (size_t)m * 8) = u;
    }
}

// ---- Main, R10 = R9 (barrier-free, register-disciplined, all K/V frags
// coalesced direct loads from the XCD-pinned L2) with ONE change: the
// phase fence between softmax and the V loads is relaxed from
// sched_barrier(0) to sched_barrier(0x24) = {VMEM_READ | SALU} may cross,
// letting the compiler hoist V loads into the QK/softmax region. This
// hides V's ~300-400cyc L2 latency under softmax VALU -- worth most in
// the low-depth tail where few co-resident waves cover latency. Register
// growth bounded (+32 transient vf regs against the 128 cap).
//   Kept: XCD pin (x=h), complementary qtile pairing, l = P.1 on the MFMA
//   pipe, diag-specialized mask (provably the last tile only), setprio.
template <bool PRE>
__global__ __launch_bounds__(256, 4) void fattn_kernel(
    const float* __restrict__ Q, const unsigned short* __restrict__ Kbf,
    const unsigned short* __restrict__ Vt, const float* __restrict__ Kf,
    const float* __restrict__ Vf, float* __restrict__ Out)
{
    const int tid  = threadIdx.x;
    const int wave = tid >> 6;
    const int lane = tid & 63;
    const int ln   = lane & 15;
    const int quad = lane >> 4;
    const int h = blockIdx.x;            // id%8 == h%8 -> per-(b,h) XCD pin
    const int b = blockIdx.z;
    // Complementary pairing (bijective in y for fixed (x,z)): co-resident
    // blocks get qtiles {t, 15-t, (t+8)&15, 15-((t+8)&15)} -> equal per-CU work.
    const int tt = (blockIdx.y + ((blockIdx.z >> 1) << 3)) & 15;
    const int qtile = (blockIdx.z & 1) ? (15 - tt) : tt;
    const int q0 = qtile * 128;
    const int qw = q0 + wave * 32;       // this wave's 32 q-rows
    const int p7 = ln & 7;

    // Q fragments (B-operand for S^T; n=ln, k=c*32+quad*8+j), pre-scaled.
    FragU qf[2][2];
    #pragma unroll
    for (int g = 0; g < 2; ++g) {
        const float* qp = Q + (((size_t)b * L_ + (qw + g * 16 + ln)) * H_ + h) * E_;
        #pragma unroll
        for (int c = 0; c < 2; ++c) {
            const int e0 = c * 32 + quad * 8;
            f32x4 lo = *(const f32x4*)(qp + e0);
            f32x4 hi = *(const f32x4*)(qp + e0 + 4);
            ushort8 u;
            u[0]=f2bf(lo[0]*SCALE2); u[1]=f2bf(lo[1]*SCALE2);
            u[2]=f2bf(lo[2]*SCALE2); u[3]=f2bf(lo[3]*SCALE2);
            u[4]=f2bf(hi[0]*SCALE2); u[5]=f2bf(hi[1]*SCALE2);
            u[6]=f2bf(hi[2]*SCALE2); u[7]=f2bf(hi[3]*SCALE2);
            qf[g][c].u = u;
        }
    }

    FragU onef;                          // all-ones bf16 B-frag for l = P.1
    #pragma unroll
    for (int j = 0; j < 8; ++j) onef.u[j] = 0x3F80;

    f32x4 o[2][4];
    #pragma unroll
    for (int g = 0; g < 2; ++g)
        #pragma unroll
        for (int et = 0; et < 4; ++et) o[g][et] = f32x4{0.f, 0.f, 0.f, 0.f};
    f32x4 lacc[2];
    lacc[0] = f32x4{0.f, 0.f, 0.f, 0.f};
    lacc[1] = f32x4{0.f, 0.f, 0.f, 0.f};

    const unsigned short* kbh = Kbf + (size_t)(b * H_ + h) * S_ * E_;
    const unsigned short* vbh = Vt  + (size_t)(b * H_ + h) * (S_ * E_);
    const float* kf32 = Kf + (((size_t)b * S_) * H_ + h) * E_;
    const float* vf32 = Vf + (((size_t)b * S_) * H_ + h) * E_;

    // Tiles this wave needs: keys 0 .. qw+31; the LAST tile is provably the
    // only one needing the causal mask (k0 mult of 64, qw mult of 32).
    const int ntw = ((qw + 31) >> 6) + 1;

    auto tile = [&](int kt, auto masked) {
        const int k0 = kt * 64;
        // ---- Phase 1: K frags, 8 coalesced 16B loads (2KB span per pair).
        FragU kf[8];
        if constexpr (PRE) {
            #pragma unroll
            for (int n = 0; n < 4; ++n) {
                const unsigned short* kr = kbh + (size_t)(k0 + n * 16 + ln) * E_;
                kf[2*n  ].u = *(const ushort8*)(kr + ((quad    ) ^ p7) * 8);
                kf[2*n+1].u = *(const ushort8*)(kr + ((4 + quad) ^ p7) * 8);
            }
        } else {
            #pragma unroll
            for (int n = 0; n < 4; ++n) {
                const float* kr = kf32 + (size_t)(k0 + n * 16 + ln) * (H_ * E_);
                #pragma unroll
                for (int c = 0; c < 2; ++c) {
                    f32x4 a = *(const f32x4*)(kr + (c * 4 + quad) * 8);
                    f32x4 d = *(const f32x4*)(kr + (c * 4 + quad) * 8 + 4);
                    ushort8 u;
                    u[0]=f2bf(a[0]); u[1]=f2bf(a[1]); u[2]=f2bf(a[2]); u[3]=f2bf(a[3]);
                    u[4]=f2bf(d[0]); u[5]=f2bf(d[1]); u[6]=f2bf(d[2]); u[7]=f2bf(d[3]);
                    kf[2*n+c].u = u;
                }
            }
        }
        // ---- Phase 2: S^T = K.Q^T + softmax; kf[2n..] die per n.
        FragU pf[2][2];
        __builtin_amdgcn_s_setprio(1);
        #pragma unroll
        for (int n = 0; n < 4; ++n) {
            #pragma unroll
            for (int g = 0; g < 2; ++g) {
                f32x4 acc = f32x4{0.f, 0.f, 0.f, 0.f};
                acc = __builtin_amdgcn_mfma_f32_16x16x32_bf16(kf[2*n].b,   qf[g][0].b, acc, 0, 0, 0);
                acc = __builtin_amdgcn_mfma_f32_16x16x32_bf16(kf[2*n+1].b, qf[g][1].b, acc, 0, 0, 0);
                float p[4];
                #pragma unroll
                for (int r = 0; r < 4; ++r) {
                    float v = __builtin_exp2f(acc[r]);
                    if constexpr (decltype(masked)::value) {
                        const int key  = k0 + n * 16 + quad * 4 + r;
                        const int qrow = qw + g * 16 + ln;
                        v = (key <= qrow) ? v : 0.f;
                    }
                    p[r] = v;
                }
                pf[g][n >> 1].d[(n & 1) * 2 + 0] = pack_bf(p[1], p[0]);
                pf[g][n >> 1].d[(n & 1) * 2 + 1] = pack_bf(p[3], p[2]);
            }
        }
        __builtin_amdgcn_s_setprio(0);
        // Relaxed fence: VALU/MFMA order pinned (softmax before PV), but
        // VMEM_READ|SALU may cross -- V loads hoist into the softmax region
        // so their L2 latency hides under the exp2/pack VALU chain.
        __builtin_amdgcn_sched_barrier(0x24);

        // ---- Phase 3: V frags, 8 x 1KB contiguous loads.
        FragU vf[8];
        if constexpr (PRE) {
            const unsigned short* vtb = vbh + (size_t)kt * 4096;
            #pragma unroll
            for (int m = 0; m < 8; ++m)
                vf[m].u = *(const ushort8*)(vtb + m * 512 + lane * 8);
        } else {
            #pragma unroll
            for (int et = 0; et < 4; ++et) {
                #pragma unroll
                for (int c = 0; c < 2; ++c) {
                    ushort8 u;
                    #pragma unroll
                    for (int j = 0; j < 8; ++j) {
                        const int key = k0 + (2 * c + (j >> 2)) * 16 + quad * 4 + (j & 3);
                        u[j] = f2bf(vf32[(size_t)key * (H_ * E_) + et * 16 + ln]);
                    }
                    vf[2*et+c].u = u;
                }
            }
        }
        // ---- Phase 4: l += P.1 ; O += P.V.
        __builtin_amdgcn_s_setprio(1);
        #pragma unroll
        for (int g = 0; g < 2; ++g) {
            lacc[g] = __builtin_amdgcn_mfma_f32_16x16x32_bf16(pf[g][0].b, onef.b, lacc[g], 0, 0, 0);
            lacc[g] = __builtin_amdgcn_mfma_f32_16x16x32_bf16(pf[g][1].b, onef.b, lacc[g], 0, 0, 0);
        }
        #pragma unroll
        for (int et = 0; et < 4; ++et) {
            #pragma unroll
            for (int g = 0; g < 2; ++g) {
                o[g][et] = __builtin_amdgcn_mfma_f32_16x16x32_bf16(pf[g][0].b, vf[2*et].b,   o[g][et], 0, 0, 0);
                o[g][et] = __builtin_amdgcn_mfma_f32_16x16x32_bf16(pf[g][1].b, vf[2*et+1].b, o[g][et], 0, 0, 0);
            }
        }
        __builtin_amdgcn_s_setprio(0);
    };

    for (int kt = 0; kt + 1 < ntw; ++kt)
        tile(kt, std::integral_constant<bool, false>{});
    tile(ntw - 1, std::integral_constant<bool, true>{});

    // Epilogue: lacc[g][r] holds l for row quad*4+r of group g on THIS lane
    // (C-layout row = quad*4 + reg, every col identical) -- no shuffles.
    #pragma unroll
    for (int g = 0; g < 2; ++g) {
        #pragma unroll
        for (int r = 0; r < 4; ++r) {
            const float invr = 1.f / lacc[g][r];
            float* op = Out + (((size_t)b * L_ + (qw + g * 16 + quad * 4 + r)) * H_ + h) * E_;
            #pragma unroll
            for (int et = 0; et < 4; ++et)
                op[et * 16 + ln] = o[g][et][r] * invr;
        }
    }
}

extern "C" void kernel_launch(void* const* d_in, const int* in_sizes, int n_in,
                              void* d_out, int out_size, void* d_ws, size_t ws_size,
                              hipStream_t stream) {
    const float* Q = (const float*)d_in[0];
    const float* K = (const float*)d_in[1];
    const float* V = (const float*)d_in[2];
    // d_in[3] (causal mask) applied analytically in-kernel.
    float* Out = (float*)d_out;

    const size_t plane = (size_t)B_ * H_ * S_ * E_;
    unsigned short* Kbf = (unsigned short*)d_ws;
    unsigned short* Vt  = Kbf + plane;

    dim3 grid(H_, L_ / 128, B_);         // x = head: pins (b,h) to one XCD
    if (ws_size >= plane * 2 * sizeof(unsigned short)) {
        conv_kv<<<B_ * H_ * (S_ / 64), 256, 0, stream>>>(K, V, Kbf, Vt);
        fattn_kernel<true><<<grid, dim3(256), 0, stream>>>(Q, Kbf, Vt, K, V, Out);
    } else {
        fattn_kernel<false><<<grid, dim3(256), 0, stream>>>(Q, Kbf, Vt, K, V, Out);
    }
}